// Round 1
// baseline (331.967 us; speedup 1.0000x reference)
//
#include <hip/hip_runtime.h>
#include <hip/hip_bf16.h>

// CausalAttention MI355X: B=2 L=2048 D=1024 H=16 HD=64
// Pipeline: convert -> QKV GEMM (bf16 MFMA) -> flash attention -> out GEMM.

using bf16x8 = __attribute__((ext_vector_type(8))) short;
using f32x4  = __attribute__((ext_vector_type(4))) float;

static __device__ __forceinline__ unsigned short f2b(float f) {
  // round-to-nearest-even bf16 (finite values only)
  unsigned u = __builtin_bit_cast(unsigned, f);
  unsigned r = (u + 0x7fffu + ((u >> 16) & 1u)) >> 16;
  return (unsigned short)r;
}

// ---------------------------------------------------------------- converts
__global__ __launch_bounds__(256) void convert_bf16(
    const float* __restrict__ in, unsigned short* __restrict__ out, int n8) {
  int i = blockIdx.x * 256 + threadIdx.x;
  if (i >= n8) return;
  const float4* p = reinterpret_cast<const float4*>(in) + (size_t)i * 2;
  float4 a = p[0], b = p[1];
  bf16x8 o;
  o[0] = f2b(a.x); o[1] = f2b(a.y); o[2] = f2b(a.z); o[3] = f2b(a.w);
  o[4] = f2b(b.x); o[5] = f2b(b.y); o[6] = f2b(b.z); o[7] = f2b(b.w);
  reinterpret_cast<bf16x8*>(out)[i] = o;
}

// w [K][N] fp32 -> wt [N][K] bf16. Lane-consecutive n => coalesced reads;
// each thread writes one contiguous 16B chunk of wt.
__global__ __launch_bounds__(256) void transpose_convert(
    const float* __restrict__ w, unsigned short* __restrict__ wt, int K, int N) {
  int idx = blockIdx.x * 256 + threadIdx.x;
  int n  = idx % N;
  int k0 = (idx / N) * 8;
  if (k0 >= K) return;
  bf16x8 o;
#pragma unroll
  for (int j = 0; j < 8; ++j) o[j] = f2b(w[(size_t)(k0 + j) * N + n]);
  *reinterpret_cast<bf16x8*>(&wt[(size_t)n * K + k0]) = o;
}

// ---------------------------------------------------------------- GEMM
// C[M][N] = A[M][1024] * Bt[N][1024]^T + bias.  128x128 tile, 4 waves of
// 64x64, BK=64, LDS pad +8 elems (stride 144B, 16B-aligned, spreads banks).
// mode 0: scatter to q (x0.125)/k/v(transposed) bf16.  mode 1: fp32 out.
__global__ __launch_bounds__(256) void gemm128(
    const unsigned short* __restrict__ A,
    const unsigned short* __restrict__ Bt,
    const float* __restrict__ bias, int mode,
    unsigned short* __restrict__ qb, unsigned short* __restrict__ kb,
    unsigned short* __restrict__ vt, float* __restrict__ outf) {
  __shared__ __align__(16) unsigned short lA[128][72];
  __shared__ __align__(16) unsigned short lB[128][72];
  const int t = threadIdx.x;
  const int bn = blockIdx.x, bm = blockIdx.y;
  const int w = t >> 6, lane = t & 63;
  const int lr = lane & 15, lg = lane >> 4;
  const int wm = (w >> 1) * 64, wn = (w & 1) * 64;

  f32x4 acc[4][4];
#pragma unroll
  for (int i = 0; i < 4; ++i)
#pragma unroll
    for (int j = 0; j < 4; ++j) acc[i][j] = f32x4{0.f, 0.f, 0.f, 0.f};

  const size_t am = (size_t)bm * 128, bnr = (size_t)bn * 128;
  const int srow = t >> 3, scol = (t & 7) * 8;

  for (int k0 = 0; k0 < 1024; k0 += 64) {
#pragma unroll
    for (int p = 0; p < 4; ++p) {
      int row = p * 32 + srow;
      *reinterpret_cast<bf16x8*>(&lA[row][scol]) =
          *reinterpret_cast<const bf16x8*>(&A[(am + row) * 1024 + k0 + scol]);
      *reinterpret_cast<bf16x8*>(&lB[row][scol]) =
          *reinterpret_cast<const bf16x8*>(&Bt[(bnr + row) * 1024 + k0 + scol]);
    }
    __syncthreads();
#pragma unroll
    for (int kk = 0; kk < 64; kk += 32) {
      bf16x8 af[4], bfr[4];
#pragma unroll
      for (int fm = 0; fm < 4; ++fm)
        af[fm] = *reinterpret_cast<const bf16x8*>(&lA[wm + fm * 16 + lr][kk + lg * 8]);
#pragma unroll
      for (int fn = 0; fn < 4; ++fn)
        bfr[fn] = *reinterpret_cast<const bf16x8*>(&lB[wn + fn * 16 + lr][kk + lg * 8]);
#pragma unroll
      for (int fm = 0; fm < 4; ++fm)
#pragma unroll
        for (int fn = 0; fn < 4; ++fn)
          acc[fm][fn] = __builtin_amdgcn_mfma_f32_16x16x32_bf16(
              af[fm], bfr[fn], acc[fm][fn], 0, 0, 0);
    }
    __syncthreads();
  }

#pragma unroll
  for (int fm = 0; fm < 4; ++fm) {
#pragma unroll
    for (int fn = 0; fn < 4; ++fn) {
#pragma unroll
      for (int r = 0; r < 4; ++r) {
        int row = bm * 128 + wm + fm * 16 + lg * 4 + r;
        int col = bn * 128 + wn + fn * 16 + lr;
        float v = acc[fm][fn][r] + bias[col];
        if (mode == 1) {
          outf[(size_t)row * 1024 + col] = v;
        } else {
          int bb = row >> 11, l = row & 2047;
          int which = col >> 10, hn = col & 1023;
          int h = hn >> 6, d = hn & 63;
          int bh = bb * 16 + h;
          if (which == 0)
            qb[((size_t)bh * 2048 + l) * 64 + d] = f2b(v * 0.125f);  // exact scale
          else if (which == 1)
            kb[((size_t)bh * 2048 + l) * 64 + d] = f2b(v);
          else
            vt[((size_t)bh * 64 + d) * 2048 + l] = f2b(v);  // V transposed
        }
      }
    }
  }
}

// ---------------------------------------------------------------- attention
// Block = (b,h, 64 q-rows); 4 waves x 16 q-rows. Online softmax in-register.
// Q pre-scaled by 1/8. KV chunks of 64; only kv0==q0 chunk needs masking.
__global__ __launch_bounds__(256) void attn_kernel(
    const unsigned short* __restrict__ qb, const unsigned short* __restrict__ kb,
    const unsigned short* __restrict__ vt, unsigned short* __restrict__ attnb) {
  __shared__ __align__(16) unsigned short pl[4][16][72];
  const int bh = blockIdx.y;
  const int q0 = blockIdx.x * 64;
  const int w = threadIdx.x >> 6, lane = threadIdx.x & 63;
  const int lr = lane & 15, lg = lane >> 4;
  const int qrow_base = q0 + w * 16;
  const unsigned short* Q  = qb + (size_t)bh * 2048 * 64;
  const unsigned short* Kp = kb + (size_t)bh * 2048 * 64;
  const unsigned short* Vp = vt + (size_t)bh * 64 * 2048;

  bf16x8 qf[2];
#pragma unroll
  for (int kk = 0; kk < 2; ++kk)
    qf[kk] = *reinterpret_cast<const bf16x8*>(
        &Q[(size_t)(qrow_base + lr) * 64 + kk * 32 + lg * 8]);

  f32x4 acc[4];
#pragma unroll
  for (int i = 0; i < 4; ++i) acc[i] = f32x4{0.f, 0.f, 0.f, 0.f};
  float mrow[4], rsum[4];
#pragma unroll
  for (int r = 0; r < 4; ++r) { mrow[r] = -1e30f; rsum[r] = 0.f; }

  for (int kv0 = 0; kv0 <= q0; kv0 += 64) {
    f32x4 s[4];
#pragma unroll
    for (int i = 0; i < 4; ++i) s[i] = f32x4{0.f, 0.f, 0.f, 0.f};
#pragma unroll
    for (int kk = 0; kk < 2; ++kk)
#pragma unroll
      for (int nf = 0; nf < 4; ++nf) {
        bf16x8 kf = *reinterpret_cast<const bf16x8*>(
            &Kp[(size_t)(kv0 + nf * 16 + lr) * 64 + kk * 32 + lg * 8]);
        s[nf] = __builtin_amdgcn_mfma_f32_16x16x32_bf16(qf[kk], kf, s[nf], 0, 0, 0);
      }

    const bool diag = (kv0 == q0);
    float p[4][4];
    float rmax[4] = {-1e30f, -1e30f, -1e30f, -1e30f};
#pragma unroll
    for (int nf = 0; nf < 4; ++nf)
#pragma unroll
      for (int r = 0; r < 4; ++r) {
        float sv = s[nf][r];
        if (diag) {
          int key = kv0 + nf * 16 + lr;
          int qr  = qrow_base + lg * 4 + r;
          if (key > qr) sv = -1e30f;
        }
        p[nf][r] = sv;
        rmax[r] = fmaxf(rmax[r], sv);
      }
#pragma unroll
    for (int off = 1; off <= 8; off <<= 1)
#pragma unroll
      for (int r = 0; r < 4; ++r)
        rmax[r] = fmaxf(rmax[r], __shfl_xor(rmax[r], off));

    float scl[4], psum[4];
#pragma unroll
    for (int r = 0; r < 4; ++r) {
      float mn = fmaxf(mrow[r], rmax[r]);
      scl[r] = __expf(mrow[r] - mn);
      mrow[r] = mn;
      float ps = 0.f;
#pragma unroll
      for (int nf = 0; nf < 4; ++nf) {
        float pe = __expf(p[nf][r] - mn);
        p[nf][r] = pe;
        ps += pe;
      }
      psum[r] = ps;
    }
#pragma unroll
    for (int off = 1; off <= 8; off <<= 1)
#pragma unroll
      for (int r = 0; r < 4; ++r) psum[r] += __shfl_xor(psum[r], off);
#pragma unroll
    for (int r = 0; r < 4; ++r) rsum[r] = rsum[r] * scl[r] + psum[r];
#pragma unroll
    for (int df = 0; df < 4; ++df)
#pragma unroll
      for (int r = 0; r < 4; ++r) acc[df][r] *= scl[r];

    // D-layout -> A-layout through per-wave padded LDS tile (same wave:
    // compiler's lgkmcnt ordering suffices, no barrier).
#pragma unroll
    for (int nf = 0; nf < 4; ++nf)
#pragma unroll
      for (int r = 0; r < 4; ++r)
        pl[w][lg * 4 + r][nf * 16 + lr] = f2b(p[nf][r]);

#pragma unroll
    for (int kk = 0; kk < 2; ++kk) {
      bf16x8 pf = *reinterpret_cast<const bf16x8*>(&pl[w][lr][kk * 32 + lg * 8]);
#pragma unroll
      for (int df = 0; df < 4; ++df) {
        bf16x8 vf = *reinterpret_cast<const bf16x8*>(
            &Vp[(size_t)(df * 16 + lr) * 2048 + kv0 + kk * 32 + lg * 8]);
        acc[df] = __builtin_amdgcn_mfma_f32_16x16x32_bf16(pf, vf, acc[df], 0, 0, 0);
      }
    }
  }

  const int b = bh >> 4, h = bh & 15;
#pragma unroll
  for (int r = 0; r < 4; ++r) {
    float inv = 1.f / rsum[r];
    int qrow = qrow_base + lg * 4 + r;
#pragma unroll
    for (int df = 0; df < 4; ++df)
      attnb[((size_t)b * 2048 + qrow) * 1024 + h * 64 + df * 16 + lr] =
          f2b(acc[df][r] * inv);
  }
}

// ---------------------------------------------------------------- launch
extern "C" void kernel_launch(void* const* d_in, const int* in_sizes, int n_in,
                              void* d_out, int out_size, void* d_ws, size_t ws_size,
                              hipStream_t stream) {
  const float* x     = (const float*)d_in[0];
  const float* w_qkv = (const float*)d_in[1];
  const float* b_qkv = (const float*)d_in[2];
  const float* w_out = (const float*)d_in[3];
  const float* b_out = (const float*)d_in[4];
  float* out = (float*)d_out;
  char* ws = (char*)d_ws;

  unsigned short* xb    = (unsigned short*)(ws);               //  8.0 MB  [4096][1024]
  unsigned short* wqkvt = (unsigned short*)(ws + 8388608);     //  6.0 MB  [3072][1024]
  unsigned short* woutt = (unsigned short*)(ws + 14680064);    //  2.0 MB  [1024][1024]
  unsigned short* qb    = (unsigned short*)(ws + 16777216);    //  8.0 MB  [32][2048][64]
  unsigned short* kb    = (unsigned short*)(ws + 25165824);    //  8.0 MB  [32][2048][64]
  unsigned short* vt    = (unsigned short*)(ws + 33554432);    //  8.0 MB  [32][64][2048]
  unsigned short* attnb = (unsigned short*)(ws + 41943040);    //  8.0 MB  [4096][1024]

  convert_bf16<<<2048, 256, 0, stream>>>(x, xb, 4194304 / 8);
  transpose_convert<<<1536, 256, 0, stream>>>(w_qkv, wqkvt, 1024, 3072);
  transpose_convert<<<512, 256, 0, stream>>>(w_out, woutt, 1024, 1024);
  gemm128<<<dim3(24, 32), 256, 0, stream>>>(xb, wqkvt, b_qkv, 0, qb, kb, vt, nullptr);
  attn_kernel<<<dim3(32, 32), 256, 0, stream>>>(qb, kb, vt, attnb);
  gemm128<<<dim3(8, 32), 256, 0, stream>>>(attnb, woutt, b_out, 1,
                                           nullptr, nullptr, nullptr, out);
}

// Round 2
// 269.803 us; speedup vs baseline: 1.2304x; 1.2304x over previous
//
#include <hip/hip_runtime.h>
#include <hip/hip_bf16.h>

// CausalAttention MI355X: B=2 L=2048 D=1024 H=16 HD=64
// convert -> QKV GEMM (bf16 MFMA) -> flash attention (swapped-operand,
// register-dbuf prefetch, CU-balanced grid) -> out GEMM.

using bf16x8 = __attribute__((ext_vector_type(8))) short;
using f32x4  = __attribute__((ext_vector_type(4))) float;

static __device__ __forceinline__ unsigned short f2b(float f) {
  unsigned u = __builtin_bit_cast(unsigned, f);
  unsigned r = (u + 0x7fffu + ((u >> 16) & 1u)) >> 16;
  return (unsigned short)r;
}

// ---------------------------------------------------------------- converts
__global__ __launch_bounds__(256) void convert_bf16(
    const float* __restrict__ in, unsigned short* __restrict__ out, int n8) {
  int i = blockIdx.x * 256 + threadIdx.x;
  if (i >= n8) return;
  const float4* p = reinterpret_cast<const float4*>(in) + (size_t)i * 2;
  float4 a = p[0], b = p[1];
  bf16x8 o;
  o[0] = f2b(a.x); o[1] = f2b(a.y); o[2] = f2b(a.z); o[3] = f2b(a.w);
  o[4] = f2b(b.x); o[5] = f2b(b.y); o[6] = f2b(b.z); o[7] = f2b(b.w);
  reinterpret_cast<bf16x8*>(out)[i] = o;
}

__global__ __launch_bounds__(256) void transpose_convert(
    const float* __restrict__ w, unsigned short* __restrict__ wt, int K, int N) {
  int idx = blockIdx.x * 256 + threadIdx.x;
  int n  = idx % N;
  int k0 = (idx / N) * 8;
  if (k0 >= K) return;
  bf16x8 o;
#pragma unroll
  for (int j = 0; j < 8; ++j) o[j] = f2b(w[(size_t)(k0 + j) * N + n]);
  *reinterpret_cast<bf16x8*>(&wt[(size_t)n * K + k0]) = o;
}

// ---------------------------------------------------------------- GEMM
__global__ __launch_bounds__(256) void gemm128(
    const unsigned short* __restrict__ A,
    const unsigned short* __restrict__ Bt,
    const float* __restrict__ bias, int mode,
    unsigned short* __restrict__ qb, unsigned short* __restrict__ kb,
    unsigned short* __restrict__ vt, float* __restrict__ outf) {
  __shared__ __align__(16) unsigned short lA[128][72];
  __shared__ __align__(16) unsigned short lB[128][72];
  const int t = threadIdx.x;
  const int bn = blockIdx.x, bm = blockIdx.y;
  const int w = t >> 6, lane = t & 63;
  const int lr = lane & 15, lg = lane >> 4;
  const int wm = (w >> 1) * 64, wn = (w & 1) * 64;

  f32x4 acc[4][4];
#pragma unroll
  for (int i = 0; i < 4; ++i)
#pragma unroll
    for (int j = 0; j < 4; ++j) acc[i][j] = f32x4{0.f, 0.f, 0.f, 0.f};

  const size_t am = (size_t)bm * 128, bnr = (size_t)bn * 128;
  const int srow = t >> 3, scol = (t & 7) * 8;

  for (int k0 = 0; k0 < 1024; k0 += 64) {
#pragma unroll
    for (int p = 0; p < 4; ++p) {
      int row = p * 32 + srow;
      *reinterpret_cast<bf16x8*>(&lA[row][scol]) =
          *reinterpret_cast<const bf16x8*>(&A[(am + row) * 1024 + k0 + scol]);
      *reinterpret_cast<bf16x8*>(&lB[row][scol]) =
          *reinterpret_cast<const bf16x8*>(&Bt[(bnr + row) * 1024 + k0 + scol]);
    }
    __syncthreads();
#pragma unroll
    for (int kk = 0; kk < 64; kk += 32) {
      bf16x8 af[4], bfr[4];
#pragma unroll
      for (int fm = 0; fm < 4; ++fm)
        af[fm] = *reinterpret_cast<const bf16x8*>(&lA[wm + fm * 16 + lr][kk + lg * 8]);
#pragma unroll
      for (int fn = 0; fn < 4; ++fn)
        bfr[fn] = *reinterpret_cast<const bf16x8*>(&lB[wn + fn * 16 + lr][kk + lg * 8]);
#pragma unroll
      for (int fm = 0; fm < 4; ++fm)
#pragma unroll
        for (int fn = 0; fn < 4; ++fn)
          acc[fm][fn] = __builtin_amdgcn_mfma_f32_16x16x32_bf16(
              af[fm], bfr[fn], acc[fm][fn], 0, 0, 0);
    }
    __syncthreads();
  }

#pragma unroll
  for (int fm = 0; fm < 4; ++fm) {
#pragma unroll
    for (int fn = 0; fn < 4; ++fn) {
#pragma unroll
      for (int r = 0; r < 4; ++r) {
        int row = bm * 128 + wm + fm * 16 + lg * 4 + r;
        int col = bn * 128 + wn + fn * 16 + lr;
        float v = acc[fm][fn][r] + bias[col];
        if (mode == 1) {
          outf[(size_t)row * 1024 + col] = v;
        } else {
          int bb = row >> 11, l = row & 2047;
          int which = col >> 10, hn = col & 1023;
          int h = hn >> 6, d = hn & 63;
          int bh = bb * 16 + h;
          if (which == 0)
            qb[((size_t)bh * 2048 + l) * 64 + d] = f2b(v * 0.125f);
          else if (which == 1)
            kb[((size_t)bh * 2048 + l) * 64 + d] = f2b(v);
          else
            vt[((size_t)bh * 64 + d) * 2048 + l] = f2b(v);
        }
      }
    }
  }
}

// ---------------------------------------------------------------- attention
// Swapped-operand flash attention. Block = (bh, 64 q-rows), 4 waves x 16 rows.
// QK^T computed as mfma(K,Q) -> S^T (keys=rows, q=cols): each lane owns one
// q-row (lr) softmax state; PV computed as mfma(V^T,P^T) -> O^T.
// K/V fragments register-double-buffered (prefetch chunk c+1 during c).
// qtile = (bx+by)&31 balances causal work across CUs.
struct KV { bf16x8 k[2][4]; bf16x8 v[2][4]; };

__global__ __launch_bounds__(256, 2) void attn_kernel(
    const unsigned short* __restrict__ qb, const unsigned short* __restrict__ kb,
    const unsigned short* __restrict__ vt, unsigned short* __restrict__ attnb) {
  __shared__ __align__(16) unsigned short pl[4][16][72];
  const int bh = blockIdx.y;
  const int qt = (blockIdx.x + blockIdx.y) & 31;
  const int q0 = qt * 64;
  const int w = threadIdx.x >> 6, lane = threadIdx.x & 63;
  const int lr = lane & 15, lg = lane >> 4;
  const int qrow = q0 + w * 16 + lr;  // this lane's q-row (n-col in S^T)

  const unsigned short* Kb = kb + (size_t)bh * 2048 * 64 + lr * 64 + lg * 8;
  const unsigned short* Vb = vt + (size_t)bh * 64 * 2048 + lr * 2048 + lg * 8;

  bf16x8 qf[2];
#pragma unroll
  for (int kk = 0; kk < 2; ++kk)
    qf[kk] = *reinterpret_cast<const bf16x8*>(
        &qb[((size_t)bh * 2048 + qrow) * 64 + kk * 32 + lg * 8]);

  f32x4 acc[4];
#pragma unroll
  for (int i = 0; i < 4; ++i) acc[i] = f32x4{0.f, 0.f, 0.f, 0.f};
  float m = -1e30f, rs = 0.f;

  auto load_kv = [&](KV& f, int kv0) {
#pragma unroll
    for (int kk = 0; kk < 2; ++kk)
#pragma unroll
      for (int nf = 0; nf < 4; ++nf)
        f.k[kk][nf] = *reinterpret_cast<const bf16x8*>(
            &Kb[(size_t)(kv0 + nf * 16) * 64 + kk * 32]);
#pragma unroll
    for (int kk = 0; kk < 2; ++kk)
#pragma unroll
      for (int df = 0; df < 4; ++df)
        f.v[kk][df] = *reinterpret_cast<const bf16x8*>(
            &Vb[(size_t)(df * 16) * 2048 + kv0 + kk * 32]);
  };

  auto compute = [&](KV& f, int kv0, bool diag) {
    f32x4 s[4];
#pragma unroll
    for (int i = 0; i < 4; ++i) s[i] = f32x4{0.f, 0.f, 0.f, 0.f};
#pragma unroll
    for (int kk = 0; kk < 2; ++kk)
#pragma unroll
      for (int nf = 0; nf < 4; ++nf)
        s[nf] = __builtin_amdgcn_mfma_f32_16x16x32_bf16(f.k[kk][nf], qf[kk], s[nf], 0, 0, 0);

    float ps[4][4];
    float mx = -1e30f;
    if (diag) {
#pragma unroll
      for (int nf = 0; nf < 4; ++nf)
#pragma unroll
        for (int r = 0; r < 4; ++r) {
          int key = kv0 + nf * 16 + lg * 4 + r;
          float sv = (key <= qrow) ? s[nf][r] : -1e30f;
          ps[nf][r] = sv;
          mx = fmaxf(mx, sv);
        }
    } else {
#pragma unroll
      for (int nf = 0; nf < 4; ++nf)
#pragma unroll
        for (int r = 0; r < 4; ++r) {
          ps[nf][r] = s[nf][r];
          mx = fmaxf(mx, s[nf][r]);
        }
    }
    mx = fmaxf(mx, __shfl_xor(mx, 16));
    mx = fmaxf(mx, __shfl_xor(mx, 32));
    float mn = fmaxf(m, mx);
    float scl = __expf(m - mn);
    m = mn;
    float ss = 0.f;
#pragma unroll
    for (int nf = 0; nf < 4; ++nf)
#pragma unroll
      for (int r = 0; r < 4; ++r) {
        float pe = __expf(ps[nf][r] - mn);
        ps[nf][r] = pe;
        ss += pe;
      }
    ss += __shfl_xor(ss, 16);
    ss += __shfl_xor(ss, 32);
    rs = rs * scl + ss;
#pragma unroll
    for (int df = 0; df < 4; ++df) acc[df] *= scl;

    // pack P^T rows: lane holds q=lr, keys nf*16+lg*4+{0..3} -> 8B writes
#pragma unroll
    for (int nf = 0; nf < 4; ++nf) {
      ushort4 pk;
      pk.x = f2b(ps[nf][0]); pk.y = f2b(ps[nf][1]);
      pk.z = f2b(ps[nf][2]); pk.w = f2b(ps[nf][3]);
      *reinterpret_cast<ushort4*>(&pl[w][lr][nf * 16 + lg * 4]) = pk;
    }
#pragma unroll
    for (int kk = 0; kk < 2; ++kk) {
      bf16x8 pf = *reinterpret_cast<const bf16x8*>(&pl[w][lr][kk * 32 + lg * 8]);
#pragma unroll
      for (int df = 0; df < 4; ++df)
        acc[df] = __builtin_amdgcn_mfma_f32_16x16x32_bf16(f.v[kk][df], pf, acc[df], 0, 0, 0);
    }
  };

  const int nc = qt + 1;
  KV fA, fB;
  load_kv(fA, 0);
  for (int c = 0; c < nc; c += 2) {
    bool lastA = (c == nc - 1);
    if (!lastA) load_kv(fB, (c + 1) * 64);
    compute(fA, c * 64, lastA);
    if (!lastA) {
      bool lastB = (c + 1 == nc - 1);
      if (!lastB) load_kv(fA, (c + 2) * 64);
      compute(fB, (c + 1) * 64, lastB);
    }
  }

  const int b = bh >> 4, h = bh & 15;
  float inv = 1.f / rs;
#pragma unroll
  for (int df = 0; df < 4; ++df) {
    ushort4 ov;
    ov.x = f2b(acc[df][0] * inv); ov.y = f2b(acc[df][1] * inv);
    ov.z = f2b(acc[df][2] * inv); ov.w = f2b(acc[df][3] * inv);
    *reinterpret_cast<ushort4*>(
        &attnb[((size_t)b * 2048 + qrow) * 1024 + h * 64 + df * 16 + lg * 4]) = ov;
  }
}

// ---------------------------------------------------------------- launch
extern "C" void kernel_launch(void* const* d_in, const int* in_sizes, int n_in,
                              void* d_out, int out_size, void* d_ws, size_t ws_size,
                              hipStream_t stream) {
  const float* x     = (const float*)d_in[0];
  const float* w_qkv = (const float*)d_in[1];
  const float* b_qkv = (const float*)d_in[2];
  const float* w_out = (const float*)d_in[3];
  const float* b_out = (const float*)d_in[4];
  float* out = (float*)d_out;
  char* ws = (char*)d_ws;

  unsigned short* xb    = (unsigned short*)(ws);               //  8.0 MB
  unsigned short* wqkvt = (unsigned short*)(ws + 8388608);     //  6.0 MB
  unsigned short* woutt = (unsigned short*)(ws + 14680064);    //  2.0 MB
  unsigned short* qb    = (unsigned short*)(ws + 16777216);    //  8.0 MB
  unsigned short* kb    = (unsigned short*)(ws + 25165824);    //  8.0 MB
  unsigned short* vt    = (unsigned short*)(ws + 33554432);    //  8.0 MB
  unsigned short* attnb = (unsigned short*)(ws + 41943040);    //  8.0 MB

  convert_bf16<<<2048, 256, 0, stream>>>(x, xb, 4194304 / 8);
  transpose_convert<<<1536, 256, 0, stream>>>(w_qkv, wqkvt, 1024, 3072);
  transpose_convert<<<512, 256, 0, stream>>>(w_out, woutt, 1024, 1024);
  gemm128<<<dim3(24, 32), 256, 0, stream>>>(xb, wqkvt, b_qkv, 0, qb, kb, vt, nullptr);
  attn_kernel<<<dim3(32, 32), 256, 0, stream>>>(qb, kb, vt, attnb);
  gemm128<<<dim3(8, 32), 256, 0, stream>>>(attnb, woutt, b_out, 1,
                                           nullptr, nullptr, nullptr, out);
}

// Round 4
// 159.180 us; speedup vs baseline: 2.0855x; 1.6950x over previous
//
#include <hip/hip_runtime.h>
#include <hip/hip_bf16.h>

// CausalAttention MI355X: B=2 L=2048 D=1024 H=16 HD=64
// convert -> QKV GEMM (global_load_lds + swizzle) -> flash attention
// (LDS-staged K/V, 2-phase pipeline, swapped-operand softmax) -> out GEMM.

using bf16x8 = __attribute__((ext_vector_type(8))) short;
using f32x4  = __attribute__((ext_vector_type(4))) float;

static __device__ __forceinline__ unsigned short f2b(float f) {
  unsigned u = __builtin_bit_cast(unsigned, f);
  unsigned r = (u + 0x7fffu + ((u >> 16) & 1u)) >> 16;
  return (unsigned short)r;
}

// async global->LDS, 16B per lane. Dest must be linear (base + lane*16);
// swizzling is applied on the per-lane SOURCE address + on ds_read (rule 21).
static __device__ __forceinline__ void gl_lds16(const void* g, void* l) {
  __builtin_amdgcn_global_load_lds(
      (const __attribute__((address_space(1))) unsigned int*)g,
      (__attribute__((address_space(3))) unsigned int*)l, 16, 0, 0);
}

// ---------------------------------------------------------------- converts
__global__ __launch_bounds__(256) void convert_bf16(
    const float* __restrict__ in, unsigned short* __restrict__ out, int n8) {
  int i = blockIdx.x * 256 + threadIdx.x;
  if (i >= n8) return;
  const float4* p = reinterpret_cast<const float4*>(in) + (size_t)i * 2;
  float4 a = p[0], b = p[1];
  bf16x8 o;
  o[0] = f2b(a.x); o[1] = f2b(a.y); o[2] = f2b(a.z); o[3] = f2b(a.w);
  o[4] = f2b(b.x); o[5] = f2b(b.y); o[6] = f2b(b.z); o[7] = f2b(b.w);
  reinterpret_cast<bf16x8*>(out)[i] = o;
}

__global__ __launch_bounds__(256) void transpose_convert(
    const float* __restrict__ w, unsigned short* __restrict__ wt, int K, int N) {
  int idx = blockIdx.x * 256 + threadIdx.x;
  int n  = idx % N;
  int k0 = (idx / N) * 8;
  if (k0 >= K) return;
  bf16x8 o;
#pragma unroll
  for (int j = 0; j < 8; ++j) o[j] = f2b(w[(size_t)(k0 + j) * N + n]);
  *reinterpret_cast<bf16x8*>(&wt[(size_t)n * K + k0]) = o;
}

// ---------------------------------------------------------------- GEMM
// m97 structure: 128x128 tile, BK=64, global_load_lds staging into linear
// LDS with source-side XOR swizzle; ds_read_b128 applies the same XOR.
__global__ __launch_bounds__(256) void gemm128(
    const unsigned short* __restrict__ A,
    const unsigned short* __restrict__ Bt,
    const float* __restrict__ bias, int mode,
    unsigned short* __restrict__ qb, unsigned short* __restrict__ kb,
    unsigned short* __restrict__ vt, float* __restrict__ outf) {
  __shared__ __align__(16) unsigned short lA[128 * 64];
  __shared__ __align__(16) unsigned short lB[128 * 64];
  const int t = threadIdx.x;
  const int bn = blockIdx.x, bm = blockIdx.y;
  const int w = t >> 6, lane = t & 63;
  const int lr = lane & 15, lg = lane >> 4;
  const int wm = (w >> 1) * 64, wn = (w & 1) * 64;
  const int srow = w * 8 + (lane >> 3);   // +32 per issue
  const int sbc  = (lane & 7) * 16;       // linear dest byte col

  f32x4 acc[4][4];
#pragma unroll
  for (int i = 0; i < 4; ++i)
#pragma unroll
    for (int j = 0; j < 4; ++j) acc[i][j] = f32x4{0.f, 0.f, 0.f, 0.f};

  const size_t am = (size_t)bm * 128, bnr = (size_t)bn * 128;

  for (int k0 = 0; k0 < 1024; k0 += 64) {
#pragma unroll
    for (int i = 0; i < 4; ++i) {
      int row = i * 32 + srow;
      int sc = sbc ^ ((row & 7) << 4);
      gl_lds16((const char*)(A + (am + row) * 1024 + k0) + sc,
               (char*)lA + row * 128 + sbc);
      gl_lds16((const char*)(Bt + (bnr + row) * 1024 + k0) + sc,
               (char*)lB + row * 128 + sbc);
    }
    __syncthreads();
#pragma unroll
    for (int kk = 0; kk < 64; kk += 32) {
      bf16x8 af[4], bfr[4];
#pragma unroll
      for (int fm = 0; fm < 4; ++fm) {
        int row = wm + fm * 16 + lr;
        af[fm] = *reinterpret_cast<const bf16x8*>(
            (const char*)lA + row * 128 + ((2 * kk + lg * 16) ^ ((lr & 7) << 4)));
      }
#pragma unroll
      for (int fn = 0; fn < 4; ++fn) {
        int row = wn + fn * 16 + lr;
        bfr[fn] = *reinterpret_cast<const bf16x8*>(
            (const char*)lB + row * 128 + ((2 * kk + lg * 16) ^ ((lr & 7) << 4)));
      }
#pragma unroll
      for (int fm = 0; fm < 4; ++fm)
#pragma unroll
        for (int fn = 0; fn < 4; ++fn)
          acc[fm][fn] = __builtin_amdgcn_mfma_f32_16x16x32_bf16(
              af[fm], bfr[fn], acc[fm][fn], 0, 0, 0);
    }
    __syncthreads();
  }

#pragma unroll
  for (int fm = 0; fm < 4; ++fm) {
#pragma unroll
    for (int fn = 0; fn < 4; ++fn) {
#pragma unroll
      for (int r = 0; r < 4; ++r) {
        int row = bm * 128 + wm + fm * 16 + lg * 4 + r;
        int col = bn * 128 + wn + fn * 16 + lr;
        float v = acc[fm][fn][r] + bias[col];
        if (mode == 1) {
          outf[(size_t)row * 1024 + col] = v;
        } else {
          int bb = row >> 11, l = row & 2047;
          int which = col >> 10, hn = col & 1023;
          int h = hn >> 6, d = hn & 63;
          int bh = bb * 16 + h;
          if (which == 0)
            qb[((size_t)bh * 2048 + l) * 64 + d] = f2b(v * 0.125f);
          else if (which == 1)
            kb[((size_t)bh * 2048 + l) * 64 + d] = f2b(v);
          else
            vt[((size_t)bh * 64 + d) * 2048 + l] = f2b(v);
        }
      }
    }
  }
}

// ---------------------------------------------------------------- attention
// Block = 4 waves x 32 q-rows = 128 rows. K/V^T 64x64 chunk tiles staged in
// LDS (double-buffered, global_load_lds w/ source swizzle). Swapped-operand:
// S^T = mfma(K,Q), O^T = mfma(V^T,P^T); each lane owns one q-row's softmax.
// qt pairing (bh<16 ? bx : 15-bx) balances causal work: const 36 chunks/CU.
__global__ __launch_bounds__(256, 2) void attn_kernel(
    const unsigned short* __restrict__ qb, const unsigned short* __restrict__ kb,
    const unsigned short* __restrict__ vt, unsigned short* __restrict__ attnb) {
  __shared__ __align__(16) unsigned short lK[2][64 * 64];
  __shared__ __align__(16) unsigned short lV[2][64 * 64];
  __shared__ __align__(16) unsigned short pl[4][2][16][72];
  const int bh = blockIdx.y;
  const int qt = (bh < 16) ? blockIdx.x : (15 - (int)blockIdx.x);
  const int q0 = qt * 128;
  const int w = threadIdx.x >> 6, lane = threadIdx.x & 63;
  const int lr = lane & 15, lg = lane >> 4;
  const int srow = w * 8 + (lane >> 3);   // +32 per issue
  const int sbc  = (lane & 7) * 16;

  const unsigned short* Kg = kb + (size_t)bh * 2048 * 64;
  const unsigned short* Vg = vt + (size_t)bh * 64 * 2048;

  auto stage = [&](int buf, int c) {
    int kv0 = c * 64;
#pragma unroll
    for (int i = 0; i < 2; ++i) {
      int row = i * 32 + srow;
      int sc = sbc ^ ((row & 7) << 4);
      gl_lds16((const char*)(Kg + (size_t)(kv0 + row) * 64) + sc,
               (char*)&lK[buf][0] + row * 128 + sbc);
      gl_lds16((const char*)(Vg + (size_t)row * 2048 + kv0) + sc,
               (char*)&lV[buf][0] + row * 128 + sbc);
    }
  };

  bf16x8 qf[2][2];
#pragma unroll
  for (int qi = 0; qi < 2; ++qi)
#pragma unroll
    for (int kk = 0; kk < 2; ++kk)
      qf[qi][kk] = *reinterpret_cast<const bf16x8*>(
          &qb[((size_t)bh * 2048 + q0 + w * 32 + qi * 16 + lr) * 64 + kk * 32 + lg * 8]);

  f32x4 acc[2][4];
#pragma unroll
  for (int qi = 0; qi < 2; ++qi)
#pragma unroll
    for (int i = 0; i < 4; ++i) acc[qi][i] = f32x4{0.f, 0.f, 0.f, 0.f};
  float m[2] = {-1e30f, -1e30f}, rs[2] = {0.f, 0.f};

  const int nc = 2 * qt + 2;
  stage(0, 0);

  for (int c = 0; c < nc; ++c) {
    const int cur = c & 1;
    __syncthreads();                       // buf[cur] ready; prev reads done
    if (c + 1 < nc) stage(cur ^ 1, c + 1); // loads fly across compute

    bf16x8 kf[2][4], vf[2][4];
#pragma unroll
    for (int kk = 0; kk < 2; ++kk)
#pragma unroll
      for (int nf = 0; nf < 4; ++nf) {
        int row = nf * 16 + lr;
        int bc = (64 * kk + lg * 16) ^ ((lr & 7) << 4);
        kf[kk][nf] = *reinterpret_cast<const bf16x8*>(
            (const char*)&lK[cur][0] + row * 128 + bc);
        vf[kk][nf] = *reinterpret_cast<const bf16x8*>(
            (const char*)&lV[cur][0] + row * 128 + bc);
      }

    f32x4 s[2][4];
#pragma unroll
    for (int qi = 0; qi < 2; ++qi)
#pragma unroll
      for (int i = 0; i < 4; ++i) s[qi][i] = f32x4{0.f, 0.f, 0.f, 0.f};
#pragma unroll
    for (int qi = 0; qi < 2; ++qi)
#pragma unroll
      for (int kk = 0; kk < 2; ++kk)
#pragma unroll
        for (int nf = 0; nf < 4; ++nf)
          s[qi][nf] = __builtin_amdgcn_mfma_f32_16x16x32_bf16(
              kf[kk][nf], qf[qi][kk], s[qi][nf], 0, 0, 0);

#pragma unroll
    for (int qi = 0; qi < 2; ++qi) {
      const int qrow = q0 + w * 32 + qi * 16 + lr;
      // mask needed iff chunk's max key can exceed the group's MIN row
      // (key_max > row_min). Mask predicate itself is always safe.
      const bool diag = (c * 64 + 63) > (q0 + w * 32 + qi * 16);
      float ps[4][4];
      float mx = -1e30f;
      if (diag) {
#pragma unroll
        for (int nf = 0; nf < 4; ++nf)
#pragma unroll
          for (int r = 0; r < 4; ++r) {
            int key = c * 64 + nf * 16 + lg * 4 + r;
            float sv = (key <= qrow) ? s[qi][nf][r] : -1e30f;
            ps[nf][r] = sv;
            mx = fmaxf(mx, sv);
          }
      } else {
#pragma unroll
        for (int nf = 0; nf < 4; ++nf)
#pragma unroll
          for (int r = 0; r < 4; ++r) {
            ps[nf][r] = s[qi][nf][r];
            mx = fmaxf(mx, ps[nf][r]);
          }
      }
      mx = fmaxf(mx, __shfl_xor(mx, 16));
      mx = fmaxf(mx, __shfl_xor(mx, 32));
      float mn = fmaxf(m[qi], mx);
      float scl = __expf(m[qi] - mn);
      m[qi] = mn;
      float ss = 0.f;
#pragma unroll
      for (int nf = 0; nf < 4; ++nf)
#pragma unroll
        for (int r = 0; r < 4; ++r) {
          float pe = __expf(ps[nf][r] - mn);
          ps[nf][r] = pe;
          ss += pe;
        }
      ss += __shfl_xor(ss, 16);
      ss += __shfl_xor(ss, 32);
      rs[qi] = rs[qi] * scl + ss;
#pragma unroll
      for (int df = 0; df < 4; ++df) acc[qi][df] *= scl;
#pragma unroll
      for (int nf = 0; nf < 4; ++nf) {
        ushort4 pk;
        pk.x = f2b(ps[nf][0]); pk.y = f2b(ps[nf][1]);
        pk.z = f2b(ps[nf][2]); pk.w = f2b(ps[nf][3]);
        *reinterpret_cast<ushort4*>(&pl[w][qi][lr][nf * 16 + lg * 4]) = pk;
      }
    }

#pragma unroll
    for (int qi = 0; qi < 2; ++qi)
#pragma unroll
      for (int kk = 0; kk < 2; ++kk) {
        bf16x8 pf = *reinterpret_cast<const bf16x8*>(&pl[w][qi][lr][kk * 32 + lg * 8]);
#pragma unroll
        for (int df = 0; df < 4; ++df)
          acc[qi][df] = __builtin_amdgcn_mfma_f32_16x16x32_bf16(
              vf[kk][df], pf, acc[qi][df], 0, 0, 0);
      }
  }

  const int b = bh >> 4, h = bh & 15;
#pragma unroll
  for (int qi = 0; qi < 2; ++qi) {
    float inv = 1.f / rs[qi];
    int qrow = q0 + w * 32 + qi * 16 + lr;
#pragma unroll
    for (int df = 0; df < 4; ++df) {
      ushort4 ov;
      ov.x = f2b(acc[qi][df][0] * inv); ov.y = f2b(acc[qi][df][1] * inv);
      ov.z = f2b(acc[qi][df][2] * inv); ov.w = f2b(acc[qi][df][3] * inv);
      *reinterpret_cast<ushort4*>(
          &attnb[((size_t)b * 2048 + qrow) * 1024 + h * 64 + df * 16 + lg * 4]) = ov;
    }
  }
}

// ---------------------------------------------------------------- launch
extern "C" void kernel_launch(void* const* d_in, const int* in_sizes, int n_in,
                              void* d_out, int out_size, void* d_ws, size_t ws_size,
                              hipStream_t stream) {
  const float* x     = (const float*)d_in[0];
  const float* w_qkv = (const float*)d_in[1];
  const float* b_qkv = (const float*)d_in[2];
  const float* w_out = (const float*)d_in[3];
  const float* b_out = (const float*)d_in[4];
  float* out = (float*)d_out;
  char* ws = (char*)d_ws;

  unsigned short* xb    = (unsigned short*)(ws);               //  8.0 MB
  unsigned short* wqkvt = (unsigned short*)(ws + 8388608);     //  6.0 MB
  unsigned short* woutt = (unsigned short*)(ws + 14680064);    //  2.0 MB
  unsigned short* qb    = (unsigned short*)(ws + 16777216);    //  8.0 MB
  unsigned short* kb    = (unsigned short*)(ws + 25165824);    //  8.0 MB
  unsigned short* vt    = (unsigned short*)(ws + 33554432);    //  8.0 MB
  unsigned short* attnb = (unsigned short*)(ws + 41943040);    //  8.0 MB

  convert_bf16<<<2048, 256, 0, stream>>>(x, xb, 4194304 / 8);
  transpose_convert<<<1536, 256, 0, stream>>>(w_qkv, wqkvt, 1024, 3072);
  transpose_convert<<<512, 256, 0, stream>>>(w_out, woutt, 1024, 1024);
  gemm128<<<dim3(24, 32), 256, 0, stream>>>(xb, wqkvt, b_qkv, 0, qb, kb, vt, nullptr);
  attn_kernel<<<dim3(16, 32), 256, 0, stream>>>(qb, kb, vt, attnb);
  gemm128<<<dim3(8, 32), 256, 0, stream>>>(attnb, woutt, b_out, 1,
                                           nullptr, nullptr, nullptr, out);
}